// Round 1
// baseline (204.499 us; speedup 1.0000x reference)
//
#include <hip/hip_runtime.h>
#include <hip/hip_bf16.h>

#define FEAT 64

// ---------------------------------------------------------------------------
// Kernel 1: inverse L2 norms.  One wave (64 lanes) per row; lane = feature dim.
// ---------------------------------------------------------------------------
__global__ void norm_kernel(const float* __restrict__ x,
                            float* __restrict__ rn, int N) {
    int row  = blockIdx.x * (blockDim.x >> 6) + (threadIdx.x >> 6);
    int lane = threadIdx.x & 63;
    if (row >= N) return;
    float v = x[row * FEAT + lane];
    float s = v * v;
    #pragma unroll
    for (int off = 32; off >= 1; off >>= 1) s += __shfl_xor(s, off);
    if (lane == 0) rn[row] = rsqrtf(s + 1e-8f);
}

// ---------------------------------------------------------------------------
// Kernel 2: SDDMM edge attention.  16 lanes per edge; each lane dots a float4
// slice of the two node rows, then a 16-lane butterfly reduce.
// att[e] = beta * rn[r] * rn[c] * dot(x[r], x[c])
// ---------------------------------------------------------------------------
__global__ void att_kernel(const float* __restrict__ x,
                           const float* __restrict__ rn,
                           const float* __restrict__ beta,
                           const int* __restrict__ row,
                           const int* __restrict__ col,
                           float* __restrict__ att, int E) {
    int idx = blockIdx.x * blockDim.x + threadIdx.x;
    int e = idx >> 4;
    int l = idx & 15;
    if (e >= E) return;
    int r = row[e];
    int c = col[e];
    const float4 a = *reinterpret_cast<const float4*>(x + (size_t)r * FEAT + l * 4);
    const float4 b = *reinterpret_cast<const float4*>(x + (size_t)c * FEAT + l * 4);
    float d = a.x * b.x + a.y * b.y + a.z * b.z + a.w * b.w;
    d += __shfl_xor(d, 1);
    d += __shfl_xor(d, 2);
    d += __shfl_xor(d, 4);
    d += __shfl_xor(d, 8);
    if (l == 0) att[e] = beta[0] * rn[r] * rn[c] * d;
}

// ---------------------------------------------------------------------------
// Kernel 3: fused segment softmax + aggregation.  One wave per destination
// row.  row_index is sorted, so each wave binary-searches its edge range.
// lane = feature dim for the aggregation phase.
// ---------------------------------------------------------------------------
__global__ void agg_kernel(const float* __restrict__ x,
                           const float* __restrict__ att,
                           const int* __restrict__ row,
                           const int* __restrict__ col,
                           float* __restrict__ out, int N, int E) {
    int r    = blockIdx.x * (blockDim.x >> 6) + (threadIdx.x >> 6);
    int lane = threadIdx.x & 63;
    if (r >= N) return;

    // lower_bound(row, r) and lower_bound(row, r+1)  (wave-uniform)
    int lo = 0, hi = E;
    while (lo < hi) { int mid = (lo + hi) >> 1; if (row[mid] < r) lo = mid + 1; else hi = mid; }
    int start = lo;
    hi = E;
    while (lo < hi) { int mid = (lo + hi) >> 1; if (row[mid] < r + 1) lo = mid + 1; else hi = mid; }
    int end = lo;

    // Phase A: segment max (lane-strided, butterfly reduce)
    float m = -INFINITY;
    for (int e = start + lane; e < end; e += 64) m = fmaxf(m, att[e]);
    #pragma unroll
    for (int off = 32; off >= 1; off >>= 1) m = fmaxf(m, __shfl_xor(m, off));

    // Phase B: segment sum of exp
    float s = 0.f;
    for (int e = start + lane; e < end; e += 64) s += __expf(att[e] - m);
    #pragma unroll
    for (int off = 32; off >= 1; off >>= 1) s += __shfl_xor(s, off);
    float inv = 1.0f / fmaxf(s, 1e-16f);

    // Phase C: weighted aggregation.  Serial over edges; 64-lane coalesced
    // load of x[col[e]] per edge.
    float acc = 0.f;
    for (int e = start; e < end; ++e) {
        float w = __expf(att[e] - m);            // broadcast (uniform addr)
        acc += w * x[(size_t)col[e] * FEAT + lane];
    }
    out[(size_t)r * FEAT + lane] = acc * inv;
}

// ---------------------------------------------------------------------------
extern "C" void kernel_launch(void* const* d_in, const int* in_sizes, int n_in,
                              void* d_out, int out_size, void* d_ws, size_t ws_size,
                              hipStream_t stream) {
    const float* x    = (const float*)d_in[0];
    const float* beta = (const float*)d_in[1];
    const int*   row  = (const int*)d_in[2];
    const int*   col  = (const int*)d_in[3];
    float*       out  = (float*)d_out;

    const int N = in_sizes[0] / FEAT;   // 50000
    const int E = in_sizes[2];          // 800000

    // Workspace layout: rn[N] floats, then att[E] floats.
    float* rn  = (float*)d_ws;
    float* att = rn + ((N + 63) & ~63);

    {   // norms: 4 rows per 256-thread block
        int rows_per_blk = 256 / 64;
        int grid = (N + rows_per_blk - 1) / rows_per_blk;
        norm_kernel<<<grid, 256, 0, stream>>>(x, rn, N);
    }
    {   // attention: 16 edges per 256-thread block
        int edges_per_blk = 256 / 16;
        int grid = (E + edges_per_blk - 1) / edges_per_blk;
        att_kernel<<<grid, 256, 0, stream>>>(x, rn, beta, row, col, att, E);
    }
    {   // softmax + aggregation: 4 rows per 256-thread block
        int rows_per_blk = 256 / 64;
        int grid = (N + rows_per_blk - 1) / rows_per_blk;
        agg_kernel<<<grid, 256, 0, stream>>>(x, att, row, col, out, N, E);
    }
}

// Round 2
// 88.468 us; speedup vs baseline: 2.3116x; 2.3116x over previous
//
#include <hip/hip_runtime.h>
#include <hip/hip_bf16.h>

#define FEAT 64

// ---------------------------------------------------------------------------
// Kernel 1: inverse L2 norms.  One wave (64 lanes) per row; lane = feature dim.
// ---------------------------------------------------------------------------
__global__ void norm_kernel(const float* __restrict__ x,
                            float* __restrict__ rn, int N) {
    int row  = blockIdx.x * (blockDim.x >> 6) + (threadIdx.x >> 6);
    int lane = threadIdx.x & 63;
    if (row >= N) return;
    float v = x[row * FEAT + lane];
    float s = v * v;
    #pragma unroll
    for (int off = 32; off >= 1; off >>= 1) s += __shfl_xor(s, off);
    if (lane == 0) rn[row] = rsqrtf(s + 1e-8f);
}

// ---------------------------------------------------------------------------
// Kernel 2: build row_ptr[N+1] from the SORTED row_index.
// row_ptr[r] = lower_bound(row, r).  Each edge writes the boundaries it
// straddles; gaps are small (Poisson(16) degrees), so loops are short.
// ---------------------------------------------------------------------------
__global__ void rowptr_kernel(const int* __restrict__ row,
                              int* __restrict__ row_ptr, int N, int E) {
    int e = blockIdx.x * blockDim.x + threadIdx.x;
    if (e >= E) return;
    int curr = row[e];
    if (e == 0) {
        for (int r = 0; r <= curr; ++r) row_ptr[r] = 0;
    } else {
        int prev = row[e - 1];
        for (int r = prev + 1; r <= curr; ++r) row_ptr[r] = e;
    }
    if (e == E - 1) {
        for (int r = curr + 1; r <= N; ++r) row_ptr[r] = E;
    }
}

// ---------------------------------------------------------------------------
// Kernel 3: SDDMM edge attention.  16 lanes per edge; each lane dots a float4
// slice of the two node rows, then a 16-lane butterfly reduce.
// att[e] = beta * rn[r] * rn[c] * dot(x[r], x[c])
// ---------------------------------------------------------------------------
__global__ void att_kernel(const float* __restrict__ x,
                           const float* __restrict__ rn,
                           const float* __restrict__ beta,
                           const int* __restrict__ row,
                           const int* __restrict__ col,
                           float* __restrict__ att, int E) {
    int idx = blockIdx.x * blockDim.x + threadIdx.x;
    int e = idx >> 4;
    int l = idx & 15;
    if (e >= E) return;
    int r = row[e];
    int c = col[e];
    const float4 a = *reinterpret_cast<const float4*>(x + (size_t)r * FEAT + l * 4);
    const float4 b = *reinterpret_cast<const float4*>(x + (size_t)c * FEAT + l * 4);
    float d = a.x * b.x + a.y * b.y + a.z * b.z + a.w * b.w;
    d += __shfl_xor(d, 1);
    d += __shfl_xor(d, 2);
    d += __shfl_xor(d, 4);
    d += __shfl_xor(d, 8);
    if (l == 0) att[e] = beta[0] * rn[r] * rn[c] * d;
}

// ---------------------------------------------------------------------------
// Kernel 4: fused segment softmax + aggregation.  One wave per destination
// row; row_ptr gives the edge range (2 loads, no binary search).
// Hot path (deg <= 64): att/col register-cached lane-parallel, weights
// broadcast via shfl, x-row gathers 4x unrolled for ILP.
// ---------------------------------------------------------------------------
__global__ void agg_kernel(const float* __restrict__ x,
                           const float* __restrict__ att,
                           const int* __restrict__ row_ptr,
                           const int* __restrict__ col,
                           float* __restrict__ out, int N) {
    int r    = blockIdx.x * (blockDim.x >> 6) + (threadIdx.x >> 6);
    int lane = threadIdx.x & 63;
    if (r >= N) return;

    int start = row_ptr[r];
    int end   = row_ptr[r + 1];
    int deg   = end - start;

    if (deg <= 64) {
        // --- hot path: whole segment fits one wave ---
        float a = -INFINITY;
        int   c = 0;
        if (lane < deg) {
            a = att[start + lane];
            c = col[start + lane];
        }
        float m = a;
        #pragma unroll
        for (int off = 32; off >= 1; off >>= 1) m = fmaxf(m, __shfl_xor(m, off));

        float w = (lane < deg) ? __expf(a - m) : 0.f;
        float s = w;
        #pragma unroll
        for (int off = 32; off >= 1; off >>= 1) s += __shfl_xor(s, off);
        float inv = 1.0f / fmaxf(s, 1e-16f);

        float acc = 0.f;
        int k = 0;
        for (; k + 4 <= deg; k += 4) {
            float w0 = __shfl(w, k),     w1 = __shfl(w, k + 1);
            float w2 = __shfl(w, k + 2), w3 = __shfl(w, k + 3);
            int   c0 = __shfl(c, k),     c1 = __shfl(c, k + 1);
            int   c2 = __shfl(c, k + 2), c3 = __shfl(c, k + 3);
            float v0 = x[(size_t)c0 * FEAT + lane];
            float v1 = x[(size_t)c1 * FEAT + lane];
            float v2 = x[(size_t)c2 * FEAT + lane];
            float v3 = x[(size_t)c3 * FEAT + lane];
            acc += w0 * v0;
            acc += w1 * v1;
            acc += w2 * v2;
            acc += w3 * v3;
        }
        for (; k < deg; ++k) {
            float wk = __shfl(w, k);
            int   ck = __shfl(c, k);
            acc += wk * x[(size_t)ck * FEAT + lane];
        }
        out[(size_t)r * FEAT + lane] = acc * inv;
    } else {
        // --- rare fallback: deg > 64, strided two-pass ---
        float m = -INFINITY;
        for (int e = start + lane; e < end; e += 64) m = fmaxf(m, att[e]);
        #pragma unroll
        for (int off = 32; off >= 1; off >>= 1) m = fmaxf(m, __shfl_xor(m, off));

        float s = 0.f;
        for (int e = start + lane; e < end; e += 64) s += __expf(att[e] - m);
        #pragma unroll
        for (int off = 32; off >= 1; off >>= 1) s += __shfl_xor(s, off);
        float inv = 1.0f / fmaxf(s, 1e-16f);

        float acc = 0.f;
        for (int e = start; e < end; ++e) {
            float wk = __expf(att[e] - m);
            acc += wk * x[(size_t)col[e] * FEAT + lane];
        }
        out[(size_t)r * FEAT + lane] = acc * inv;
    }
}

// ---------------------------------------------------------------------------
extern "C" void kernel_launch(void* const* d_in, const int* in_sizes, int n_in,
                              void* d_out, int out_size, void* d_ws, size_t ws_size,
                              hipStream_t stream) {
    const float* x    = (const float*)d_in[0];
    const float* beta = (const float*)d_in[1];
    const int*   row  = (const int*)d_in[2];
    const int*   col  = (const int*)d_in[3];
    float*       out  = (float*)d_out;

    const int N = in_sizes[0] / FEAT;   // 50000
    const int E = in_sizes[2];          // 800000

    // Workspace layout: rn[N] | att[E] | row_ptr[N+1]
    float* rn      = (float*)d_ws;
    float* att     = rn + ((N + 63) & ~63);
    int*   row_ptr = (int*)(att + ((E + 63) & ~63));

    {   // norms: 4 rows per 256-thread block
        int grid = (N + 3) / 4;
        norm_kernel<<<grid, 256, 0, stream>>>(x, rn, N);
    }
    {   // row_ptr build: edge-parallel
        int grid = (E + 255) / 256;
        rowptr_kernel<<<grid, 256, 0, stream>>>(row, row_ptr, N, E);
    }
    {   // attention: 16 edges per 256-thread block
        int grid = (E + 15) / 16;
        att_kernel<<<grid, 256, 0, stream>>>(x, rn, beta, row, col, att, E);
    }
    {   // softmax + aggregation: 4 rows per 256-thread block
        int grid = (N + 3) / 4;
        agg_kernel<<<grid, 256, 0, stream>>>(x, att, row_ptr, col, out, N);
    }
}

// Round 3
// 65.360 us; speedup vs baseline: 3.1288x; 1.3536x over previous
//
#include <hip/hip_runtime.h>
#include <hip/hip_bf16.h>

#define FEAT 64

// ---------------------------------------------------------------------------
// Kernel 1: inverse L2 norms.  One wave (64 lanes) per row; lane = feature dim.
// ---------------------------------------------------------------------------
__global__ void norm_kernel(const float* __restrict__ x,
                            float* __restrict__ rn, int N) {
    int row  = blockIdx.x * (blockDim.x >> 6) + (threadIdx.x >> 6);
    int lane = threadIdx.x & 63;
    if (row >= N) return;
    float v = x[row * FEAT + lane];
    float s = v * v;
    #pragma unroll
    for (int off = 32; off >= 1; off >>= 1) s += __shfl_xor(s, off);
    if (lane == 0) rn[row] = rsqrtf(s + 1e-8f);
}

// ---------------------------------------------------------------------------
// Kernel 2: build row_ptr[N+1] from the SORTED row_index.
// ---------------------------------------------------------------------------
__global__ void rowptr_kernel(const int* __restrict__ row,
                              int* __restrict__ row_ptr, int N, int E) {
    int e = blockIdx.x * blockDim.x + threadIdx.x;
    if (e >= E) return;
    int curr = row[e];
    if (e == 0) {
        for (int r = 0; r <= curr; ++r) row_ptr[r] = 0;
    } else {
        int prev = row[e - 1];
        for (int r = prev + 1; r <= curr; ++r) row_ptr[r] = e;
    }
    if (e == E - 1) {
        for (int r = curr + 1; r <= N; ++r) row_ptr[r] = E;
    }
}

// ---------------------------------------------------------------------------
// Kernel 3: FUSED attention + segment softmax + aggregation.
// One wave per destination row.  x[r] lives in registers (16 lanes x float4,
// replicated across the 4 16-lane groups).  Phase A computes the 4 edge dots
// per iteration (one coalesced 1KB gather), softmax stays in registers,
// phase C re-gathers x[c] (L1/L2-hot) for the weighted sum.
// ---------------------------------------------------------------------------
__global__ void fused_kernel(const float* __restrict__ x,
                             const float* __restrict__ rn,
                             const float* __restrict__ beta,
                             const int* __restrict__ row_ptr,
                             const int* __restrict__ col,
                             float* __restrict__ out, int N) {
    int r    = blockIdx.x * (blockDim.x >> 6) + (threadIdx.x >> 6);
    int lane = threadIdx.x & 63;
    if (r >= N) return;

    int start = row_ptr[r];
    int end   = row_ptr[r + 1];
    int deg   = end - start;

    float beta0 = beta[0];
    float rnr   = rn[r];

    if (deg <= 64) {
        // ---- preload this lane's edge metadata ----
        int   c_lane = 0;
        float rnc    = 0.f;
        if (lane < deg) {
            c_lane = col[start + lane];
            rnc    = rn[c_lane];
        }
        // ---- x[r] in registers: 16-lane slice layout, replicated x4 ----
        const float4 xr = *reinterpret_cast<const float4*>(
            x + (size_t)r * FEAT + (lane & 15) * 4);

        // ---- Phase A: dots, 4 edges per iteration ----
        int g = lane >> 4;             // group id: which edge of the quad
        float a = 0.f;                 // this lane's raw dot (edge start+lane)
        for (int k = 0; k < deg; k += 4) {
            int  ke    = k + g;
            bool valid = ke < deg;
            int  cc    = __shfl(c_lane, valid ? ke : 0);
            float4 v = make_float4(0.f, 0.f, 0.f, 0.f);
            if (valid)
                v = *reinterpret_cast<const float4*>(
                    x + (size_t)cc * FEAT + (lane & 15) * 4);
            float d = xr.x * v.x + xr.y * v.y + xr.z * v.z + xr.w * v.w;
            d += __shfl_xor(d, 1);
            d += __shfl_xor(d, 2);
            d += __shfl_xor(d, 4);
            d += __shfl_xor(d, 8);
            // lanes [k, k+4) capture the dot of edge (lane): edge j's dot
            // lives in group (j-k) -> source lane (j-k)*16
            float dcap = __shfl(d, (lane - k) * 16);
            if (lane >= k && lane < k + 4) a = dcap;
        }
        float att_l = (lane < deg) ? beta0 * rnr * rnc * a : -INFINITY;

        // ---- softmax in registers ----
        float m = att_l;
        #pragma unroll
        for (int off = 32; off >= 1; off >>= 1) m = fmaxf(m, __shfl_xor(m, off));
        float w = (lane < deg) ? __expf(att_l - m) : 0.f;
        float s = w;
        #pragma unroll
        for (int off = 32; off >= 1; off >>= 1) s += __shfl_xor(s, off);
        float inv = 1.0f / fmaxf(s, 1e-16f);

        // ---- Phase C: weighted aggregation (gathers are L1/L2-hot) ----
        float acc = 0.f;
        int k = 0;
        for (; k + 4 <= deg; k += 4) {
            float w0 = __shfl(w, k),     w1 = __shfl(w, k + 1);
            float w2 = __shfl(w, k + 2), w3 = __shfl(w, k + 3);
            int   c0 = __shfl(c_lane, k),     c1 = __shfl(c_lane, k + 1);
            int   c2 = __shfl(c_lane, k + 2), c3 = __shfl(c_lane, k + 3);
            float v0 = x[(size_t)c0 * FEAT + lane];
            float v1 = x[(size_t)c1 * FEAT + lane];
            float v2 = x[(size_t)c2 * FEAT + lane];
            float v3 = x[(size_t)c3 * FEAT + lane];
            acc += w0 * v0;
            acc += w1 * v1;
            acc += w2 * v2;
            acc += w3 * v3;
        }
        for (; k < deg; ++k) {
            float wk = __shfl(w, k);
            int   ck = __shfl(c_lane, k);
            acc += wk * x[(size_t)ck * FEAT + lane];
        }
        out[(size_t)r * FEAT + lane] = acc * inv;
    } else {
        // ---- rare fallback (deg > 64): two-pass, wave-dot per edge ----
        float xr_l = x[(size_t)r * FEAT + lane];
        float m = -INFINITY;
        for (int e = start; e < end; ++e) {
            float d = xr_l * x[(size_t)col[e] * FEAT + lane];
            #pragma unroll
            for (int off = 32; off >= 1; off >>= 1) d += __shfl_xor(d, off);
            float ae = beta0 * rnr * rn[col[e]] * d;
            m = fmaxf(m, ae);
        }
        float s = 0.f, acc = 0.f;
        for (int e = start; e < end; ++e) {
            int   ce = col[e];
            float v  = x[(size_t)ce * FEAT + lane];
            float d  = xr_l * v;
            #pragma unroll
            for (int off = 32; off >= 1; off >>= 1) d += __shfl_xor(d, off);
            float ae = beta0 * rnr * rn[ce] * d;
            float wk = __expf(ae - m);
            s   += wk;
            acc += wk * v;
        }
        float inv = 1.0f / fmaxf(s, 1e-16f);
        out[(size_t)r * FEAT + lane] = acc * inv;
    }
}

// ---------------------------------------------------------------------------
extern "C" void kernel_launch(void* const* d_in, const int* in_sizes, int n_in,
                              void* d_out, int out_size, void* d_ws, size_t ws_size,
                              hipStream_t stream) {
    const float* x    = (const float*)d_in[0];
    const float* beta = (const float*)d_in[1];
    const int*   row  = (const int*)d_in[2];
    const int*   col  = (const int*)d_in[3];
    float*       out  = (float*)d_out;

    const int N = in_sizes[0] / FEAT;   // 50000
    const int E = in_sizes[2];          // 800000

    // Workspace layout: rn[N] | row_ptr[N+1]
    float* rn      = (float*)d_ws;
    int*   row_ptr = (int*)(rn + ((N + 63) & ~63));

    {   // norms: 4 rows per 256-thread block
        int grid = (N + 3) / 4;
        norm_kernel<<<grid, 256, 0, stream>>>(x, rn, N);
    }
    {   // row_ptr build: edge-parallel
        int grid = (E + 255) / 256;
        rowptr_kernel<<<grid, 256, 0, stream>>>(row, row_ptr, N, E);
    }
    {   // fused attention + softmax + aggregation: 4 rows per 256-thread block
        int grid = (N + 3) / 4;
        fused_kernel<<<grid, 256, 0, stream>>>(x, rn, beta, row_ptr, col, out, N);
    }
}

// Round 4
// 48.740 us; speedup vs baseline: 4.1957x; 1.3410x over previous
//
#include <hip/hip_runtime.h>
#include <hip/hip_bf16.h>

#define FEAT 64

// ---------------------------------------------------------------------------
// Kernel 1: build row_ptr[N+1] from the SORTED row_index.
// row_ptr[r] = lower_bound(row, r).  Each edge writes the boundaries it
// straddles; gaps are small (Poisson degrees), so loops are short.
// ---------------------------------------------------------------------------
__global__ void rowptr_kernel(const int* __restrict__ row,
                              int* __restrict__ row_ptr, int N, int E) {
    int e = blockIdx.x * blockDim.x + threadIdx.x;
    if (e >= E) return;
    int curr = row[e];
    if (e == 0) {
        for (int r = 0; r <= curr; ++r) row_ptr[r] = 0;
    } else {
        int prev = row[e - 1];
        for (int r = prev + 1; r <= curr; ++r) row_ptr[r] = e;
    }
    if (e == E - 1) {
        for (int r = curr + 1; r <= N; ++r) row_ptr[r] = E;
    }
}

// ---------------------------------------------------------------------------
// Kernel 2: FULLY FUSED normalize + attention + online softmax + aggregation.
// One wave per destination row.  8 lanes per edge -> 8 edges per iteration:
//   - lane sub (0..7) holds features [sub*4..sub*4+3] and [32+sub*4..+3]
//   - one iteration: 2 coalesced float4 gathers of x[col], dot AND ||x_c||^2
//     reduced in one 3-step butterfly, online-softmax update, accumulate the
//     in-register v directly (no second gather, no att buffer, no rn buffer).
// ---------------------------------------------------------------------------
__global__ void fused_kernel(const float* __restrict__ x,
                             const float* __restrict__ beta,
                             const int* __restrict__ row_ptr,
                             const int* __restrict__ col,
                             float* __restrict__ out, int N) {
    int r    = blockIdx.x * (blockDim.x >> 6) + (threadIdx.x >> 6);
    int lane = threadIdx.x & 63;
    if (r >= N) return;

    int start = row_ptr[r];
    int deg   = row_ptr[r + 1] - start;

    if (deg == 0) {                       // empty row -> zeros (matches ref)
        out[(size_t)r * FEAT + lane] = 0.f;
        return;
    }

    float beta0 = beta[0];

    if (deg <= 64) {
        // ------------------- hot path -------------------
        int sub = lane & 7;               // position within 8-lane group
        int g   = lane >> 3;              // edge-group id (0..7)

        int c_lane = (lane < deg) ? col[start + lane] : 0;

        const float* xrp = x + (size_t)r * FEAT;
        float4 xa = *reinterpret_cast<const float4*>(xrp + sub * 4);
        float4 xb = *reinterpret_cast<const float4*>(xrp + 32 + sub * 4);

        // row norm (each 8-lane group covers the full row)
        float q = xa.x*xa.x + xa.y*xa.y + xa.z*xa.z + xa.w*xa.w
                + xb.x*xb.x + xb.y*xb.y + xb.z*xb.z + xb.w*xb.w;
        q += __shfl_xor(q, 1);
        q += __shfl_xor(q, 2);
        q += __shfl_xor(q, 4);
        float brn = beta0 * rsqrtf(q + 1e-8f);
        xa.x *= brn; xa.y *= brn; xa.z *= brn; xa.w *= brn;
        xb.x *= brn; xb.y *= brn; xb.z *= brn; xb.w *= brn;

        float  m = -INFINITY, s = 0.f;
        float4 aa = make_float4(0.f, 0.f, 0.f, 0.f);
        float4 ab = make_float4(0.f, 0.f, 0.f, 0.f);

        // prefetch iteration 0
        float4 va = make_float4(0.f, 0.f, 0.f, 0.f);
        float4 vb = make_float4(0.f, 0.f, 0.f, 0.f);
        {
            int cc = __shfl(c_lane, (g < deg) ? g : 0);
            if (g < deg) {
                const float* p = x + (size_t)cc * FEAT;
                va = *reinterpret_cast<const float4*>(p + sub * 4);
                vb = *reinterpret_cast<const float4*>(p + 32 + sub * 4);
            }
        }

        for (int k = 0; k < deg; k += 8) {
            // prefetch next 8 edges (independent of this iteration's chain)
            float4 na = make_float4(0.f, 0.f, 0.f, 0.f);
            float4 nb = make_float4(0.f, 0.f, 0.f, 0.f);
            if (k + 8 < deg) {
                int ke2 = k + 8 + g;
                int cc2 = __shfl(c_lane, (ke2 < deg) ? ke2 : 0);
                if (ke2 < deg) {
                    const float* p = x + (size_t)cc2 * FEAT;
                    na = *reinterpret_cast<const float4*>(p + sub * 4);
                    nb = *reinterpret_cast<const float4*>(p + 32 + sub * 4);
                }
            }

            int  ke    = k + g;
            bool valid = ke < deg;

            // dot(x_r_scaled, x_c) and ||x_c||^2, one fused butterfly
            float d  = xa.x*va.x + xa.y*va.y + xa.z*va.z + xa.w*va.w
                     + xb.x*vb.x + xb.y*vb.y + xb.z*vb.z + xb.w*vb.w;
            float vv = va.x*va.x + va.y*va.y + va.z*va.z + va.w*va.w
                     + vb.x*vb.x + vb.y*vb.y + vb.z*vb.z + vb.w*vb.w;
            d  += __shfl_xor(d, 1);   vv += __shfl_xor(vv, 1);
            d  += __shfl_xor(d, 2);   vv += __shfl_xor(vv, 2);
            d  += __shfl_xor(d, 4);   vv += __shfl_xor(vv, 4);

            float att = valid ? d * rsqrtf(vv + 1e-8f) : -INFINITY;

            // online softmax update (wave-wide running max/sum)
            float t = att;
            t = fmaxf(t, __shfl_xor(t, 8));
            t = fmaxf(t, __shfl_xor(t, 16));
            t = fmaxf(t, __shfl_xor(t, 32));
            float mn    = fmaxf(m, t);
            float scale = __expf(m - mn);           // exp(-inf)=0 on 1st iter
            float e     = valid ? __expf(att - mn) : 0.f;
            float u = e;
            u += __shfl_xor(u, 8);
            u += __shfl_xor(u, 16);
            u += __shfl_xor(u, 32);
            s = s * scale + u;

            aa.x = aa.x * scale + e * va.x;  aa.y = aa.y * scale + e * va.y;
            aa.z = aa.z * scale + e * va.z;  aa.w = aa.w * scale + e * va.w;
            ab.x = ab.x * scale + e * vb.x;  ab.y = ab.y * scale + e * vb.y;
            ab.z = ab.z * scale + e * vb.z;  ab.w = ab.w * scale + e * vb.w;

            m  = mn;
            va = na; vb = nb;
        }

        // cross-group sum (8 groups)
        #pragma unroll
        for (int off = 8; off <= 32; off <<= 1) {
            aa.x += __shfl_xor(aa.x, off);  aa.y += __shfl_xor(aa.y, off);
            aa.z += __shfl_xor(aa.z, off);  aa.w += __shfl_xor(aa.w, off);
            ab.x += __shfl_xor(ab.x, off);  ab.y += __shfl_xor(ab.y, off);
            ab.z += __shfl_xor(ab.z, off);  ab.w += __shfl_xor(ab.w, off);
        }
        float inv = 1.0f / fmaxf(s, 1e-16f);
        if (lane < 16) {
            float4 o = (lane < 8) ? aa : ab;   // lane*4 = feature offset
            float4 w4 = make_float4(o.x * inv, o.y * inv, o.z * inv, o.w * inv);
            *reinterpret_cast<float4*>(out + (size_t)r * FEAT + lane * 4) = w4;
        }
    } else {
        // ------------------- rare fallback: deg > 64, two-pass -------------------
        float xr_l = x[(size_t)r * FEAT + lane];
        float q = xr_l * xr_l;
        #pragma unroll
        for (int off = 32; off >= 1; off >>= 1) q += __shfl_xor(q, off);
        float brn = beta0 * rsqrtf(q + 1e-8f);

        int end = start + deg;
        float m = -INFINITY;
        for (int e = start; e < end; ++e) {
            float v  = x[(size_t)col[e] * FEAT + lane];
            float d  = xr_l * v;
            float vv = v * v;
            #pragma unroll
            for (int off = 32; off >= 1; off >>= 1) {
                d  += __shfl_xor(d, off);
                vv += __shfl_xor(vv, off);
            }
            m = fmaxf(m, brn * d * rsqrtf(vv + 1e-8f));
        }
        float s = 0.f, acc = 0.f;
        for (int e = start; e < end; ++e) {
            float v  = x[(size_t)col[e] * FEAT + lane];
            float d  = xr_l * v;
            float vv = v * v;
            #pragma unroll
            for (int off = 32; off >= 1; off >>= 1) {
                d  += __shfl_xor(d, off);
                vv += __shfl_xor(vv, off);
            }
            float w = __expf(brn * d * rsqrtf(vv + 1e-8f) - m);
            s   += w;
            acc += w * v;
        }
        out[(size_t)r * FEAT + lane] = acc / fmaxf(s, 1e-16f);
    }
}

// ---------------------------------------------------------------------------
extern "C" void kernel_launch(void* const* d_in, const int* in_sizes, int n_in,
                              void* d_out, int out_size, void* d_ws, size_t ws_size,
                              hipStream_t stream) {
    const float* x    = (const float*)d_in[0];
    const float* beta = (const float*)d_in[1];
    const int*   row  = (const int*)d_in[2];
    const int*   col  = (const int*)d_in[3];
    float*       out  = (float*)d_out;

    const int N = in_sizes[0] / FEAT;   // 50000
    const int E = in_sizes[2];          // 800000

    int* row_ptr = (int*)d_ws;          // N+1 ints

    {   // row_ptr build: edge-parallel
        int grid = (E + 255) / 256;
        rowptr_kernel<<<grid, 256, 0, stream>>>(row, row_ptr, N, E);
    }
    {   // fused normalize + attention + softmax + aggregation
        int grid = (N + 3) / 4;         // 4 row-waves per 256-thread block
        fused_kernel<<<grid, 256, 0, stream>>>(x, beta, row_ptr, col, out, N);
    }
}

// Round 5
// 47.987 us; speedup vs baseline: 4.2615x; 1.0157x over previous
//
#include <hip/hip_runtime.h>
#include <hip/hip_bf16.h>

#define FEAT 64

// ---------------------------------------------------------------------------
// Kernel 1: inverse L2 norms.  One wave per row; lane = feature dim.
// ---------------------------------------------------------------------------
__global__ void norm_kernel(const float* __restrict__ x,
                            float* __restrict__ rn, int N) {
    int row  = blockIdx.x * (blockDim.x >> 6) + (threadIdx.x >> 6);
    int lane = threadIdx.x & 63;
    if (row >= N) return;
    float v = x[row * FEAT + lane];
    float s = v * v;
    #pragma unroll
    for (int off = 32; off >= 1; off >>= 1) s += __shfl_xor(s, off);
    if (lane == 0) rn[row] = rsqrtf(s + 1e-8f);
}

// ---------------------------------------------------------------------------
// Kernel 2: build row_ptr[N+1] from the SORTED row_index.
// ---------------------------------------------------------------------------
__global__ void rowptr_kernel(const int* __restrict__ row,
                              int* __restrict__ row_ptr, int N, int E) {
    int e = blockIdx.x * blockDim.x + threadIdx.x;
    if (e >= E) return;
    int curr = row[e];
    if (e == 0) {
        for (int r = 0; r <= curr; ++r) row_ptr[r] = 0;
    } else {
        int prev = row[e - 1];
        for (int r = prev + 1; r <= curr; ++r) row_ptr[r] = e;
    }
    if (e == E - 1) {
        for (int r = curr + 1; r <= N; ++r) row_ptr[r] = E;
    }
}

// ---------------------------------------------------------------------------
// Kernel 3: FUSED attention + group-local online softmax + aggregation.
// One 8-lane group per row, 8 rows per wave.  Lane sub holds features
// [4sub,4sub+4) and [32+4sub,...).  Per edge: 2 coalesced float4 gathers,
// 3-shfl intra-group dot reduce (att then uniform in group), shuffle-free
// online softmax update, in-register accumulation.  No cross-group traffic,
// no merge, handles any degree.
// ---------------------------------------------------------------------------
__global__ void fused_kernel(const float* __restrict__ x,
                             const float* __restrict__ rn,
                             const float* __restrict__ beta,
                             const int* __restrict__ row_ptr,
                             const int* __restrict__ col,
                             float* __restrict__ out, int N) {
    int wid  = blockIdx.x * (blockDim.x >> 6) + (threadIdx.x >> 6);
    int lane = threadIdx.x & 63;
    int g    = lane >> 3;               // group id (row slot)
    int sub  = lane & 7;                // lane within group
    int r    = wid * 8 + g;
    bool rv  = (r < N);

    int start = 0, deg = 0;
    if (rv) {
        start = row_ptr[r];
        deg   = row_ptr[r + 1] - start;
    }

    const char* xB   = (const char*)x;
    uint        subo = (uint)sub << 4;  // this lane's float4 byte offset

    // col/rn chunk 0: lanes hold edges start+0..start+7 of their group's row
    int   cols8 = 0;
    float rns8  = 0.f;
    if (sub < deg) {
        cols8 = col[start + sub];
        rns8  = rn[cols8];
    }

    // x_r, normalized and beta-scaled (att = (beta*rn_r*x_r) . x_c * rn_c)
    float4 xa = make_float4(0.f, 0.f, 0.f, 0.f);
    float4 xb = make_float4(0.f, 0.f, 0.f, 0.f);
    if (rv) {
        uint roff = ((uint)r << 8) + subo;
        xa = *reinterpret_cast<const float4*>(xB + roff);
        xb = *reinterpret_cast<const float4*>(xB + roff + 128);
        float brn = beta[0] * rn[r];
        xa.x *= brn; xa.y *= brn; xa.z *= brn; xa.w *= brn;
        xb.x *= brn; xb.y *= brn; xb.z *= brn; xb.w *= brn;
    }

    float  m = -INFINITY, s = 0.f;
    float4 aa = make_float4(0.f, 0.f, 0.f, 0.f);
    float4 ab = make_float4(0.f, 0.f, 0.f, 0.f);

    // prefetch edge 0
    float4 va = make_float4(0.f, 0.f, 0.f, 0.f);
    float4 vb = make_float4(0.f, 0.f, 0.f, 0.f);
    float  rnc = __shfl(rns8, 0, 8);
    {
        int cc = __shfl(cols8, 0, 8);
        if (deg > 0) {
            uint off = ((uint)cc << 8) + subo;
            va = *reinterpret_cast<const float4*>(xB + off);
            vb = *reinterpret_cast<const float4*>(xB + off + 128);
        }
    }

    for (int k = 0; k < deg; ++k) {
        int kn = k + 1;
        // chunk reload once per 8 edges (condition is wave-uniform)
        if ((kn & 7) == 0) {
            if (kn + sub < deg) {
                cols8 = col[start + kn + sub];
                rns8  = rn[cols8];
            }
        }
        // prefetch edge kn (intra-group shuffles; independent of compute)
        int   ccn  = __shfl(cols8, kn & 7, 8);
        float rncn = __shfl(rns8,  kn & 7, 8);
        float4 na = make_float4(0.f, 0.f, 0.f, 0.f);
        float4 nb = make_float4(0.f, 0.f, 0.f, 0.f);
        if (kn < deg) {
            uint off = ((uint)ccn << 8) + subo;
            na = *reinterpret_cast<const float4*>(xB + off);
            nb = *reinterpret_cast<const float4*>(xB + off + 128);
        }

        // dot over this lane's 8 features, then 3-step intra-group reduce
        float d = xa.x*va.x + xa.y*va.y + xa.z*va.z + xa.w*va.w
                + xb.x*vb.x + xb.y*vb.y + xb.z*vb.z + xb.w*vb.w;
        d += __shfl_xor(d, 1);
        d += __shfl_xor(d, 2);
        d += __shfl_xor(d, 4);
        float att = d * rnc;            // uniform within the group

        // shuffle-free online softmax update
        float mn = fmaxf(m, att);
        float sc = __expf(m - mn);      // exp(-inf)=0 handles first edge
        float e  = __expf(att - mn);
        s = s * sc + e;
        aa.x = aa.x * sc + e * va.x;  aa.y = aa.y * sc + e * va.y;
        aa.z = aa.z * sc + e * va.z;  aa.w = aa.w * sc + e * va.w;
        ab.x = ab.x * sc + e * vb.x;  ab.y = ab.y * sc + e * vb.y;
        ab.z = ab.z * sc + e * vb.z;  ab.w = ab.w * sc + e * vb.w;
        m = mn;

        va = na; vb = nb; rnc = rncn;
    }

    // finalize: deg==0 rows give s=0, aa=0 -> out=0 (matches reference)
    float inv = 1.0f / fmaxf(s, 1e-16f);
    if (rv) {
        uint roff = ((uint)r << 8) + subo;
        *reinterpret_cast<float4*>((char*)out + roff) =
            make_float4(aa.x * inv, aa.y * inv, aa.z * inv, aa.w * inv);
        *reinterpret_cast<float4*>((char*)out + roff + 128) =
            make_float4(ab.x * inv, ab.y * inv, ab.z * inv, ab.w * inv);
    }
}

// ---------------------------------------------------------------------------
extern "C" void kernel_launch(void* const* d_in, const int* in_sizes, int n_in,
                              void* d_out, int out_size, void* d_ws, size_t ws_size,
                              hipStream_t stream) {
    const float* x    = (const float*)d_in[0];
    const float* beta = (const float*)d_in[1];
    const int*   row  = (const int*)d_in[2];
    const int*   col  = (const int*)d_in[3];
    float*       out  = (float*)d_out;

    const int N = in_sizes[0] / FEAT;   // 50000
    const int E = in_sizes[2];          // 800000

    // Workspace layout: rn[N] | row_ptr[N+1]
    float* rn      = (float*)d_ws;
    int*   row_ptr = (int*)(rn + ((N + 63) & ~63));

    {   // norms: 4 rows per 256-thread block
        int grid = (N + 3) / 4;
        norm_kernel<<<grid, 256, 0, stream>>>(x, rn, N);
    }
    {   // row_ptr build: edge-parallel
        int grid = (E + 255) / 256;
        rowptr_kernel<<<grid, 256, 0, stream>>>(row, row_ptr, N, E);
    }
    {   // fused: 8 rows per wave, 4 waves per block -> 32 rows per block
        int waves = (N + 7) / 8;
        int grid  = (waves + 3) / 4;
        fused_kernel<<<grid, 256, 0, stream>>>(x, rn, beta, row_ptr, col, out, N);
    }
}

// Round 6
// 41.710 us; speedup vs baseline: 4.9028x; 1.1505x over previous
//
#include <hip/hip_runtime.h>
#include <hip/hip_bf16.h>

#define FEAT 64

// ---------------------------------------------------------------------------
// Kernel 1 (merged prep): blocks [0, normBlocks) compute inverse L2 norms
// (8-lane group per row, 8 rows per wave, 32 rows per block); remaining
// blocks build row_ptr[N+1] from the SORTED row_index.
// ---------------------------------------------------------------------------
__global__ void prep_kernel(const float* __restrict__ x,
                            float* __restrict__ rn,
                            const int* __restrict__ row,
                            int* __restrict__ row_ptr,
                            int N, int E, int normBlocks) {
    if ((int)blockIdx.x < normBlocks) {
        int wid  = blockIdx.x * (blockDim.x >> 6) + (threadIdx.x >> 6);
        int lane = threadIdx.x & 63;
        int g    = lane >> 3;
        int sub  = lane & 7;
        int r    = wid * 8 + g;
        if (r >= N) return;
        const char* xB = (const char*)x;
        uint roff = ((uint)r << 8) + ((uint)sub << 4);
        float4 xa = *reinterpret_cast<const float4*>(xB + roff);
        float4 xb = *reinterpret_cast<const float4*>(xB + roff + 128);
        float q = xa.x*xa.x + xa.y*xa.y + xa.z*xa.z + xa.w*xa.w
                + xb.x*xb.x + xb.y*xb.y + xb.z*xb.z + xb.w*xb.w;
        q += __shfl_xor(q, 1);
        q += __shfl_xor(q, 2);
        q += __shfl_xor(q, 4);
        if (sub == 0) rn[r] = rsqrtf(q + 1e-8f);
    } else {
        int e = (blockIdx.x - normBlocks) * blockDim.x + threadIdx.x;
        if (e >= E) return;
        int curr = row[e];
        if (e == 0) {
            for (int r = 0; r <= curr; ++r) row_ptr[r] = 0;
        } else {
            int prev = row[e - 1];
            for (int r = prev + 1; r <= curr; ++r) row_ptr[r] = e;
        }
        if (e == E - 1) {
            for (int r = curr + 1; r <= N; ++r) row_ptr[r] = E;
        }
    }
}

// ---------------------------------------------------------------------------
// Kernel 2: FUSED attention + shift-free softmax + aggregation.
// One 8-lane group per row, 8 rows per wave.  att = beta*cos_sim is bounded
// by |beta| (=1), so exp(att) cannot overflow and the segment-max shift is
// algebraically redundant: alpha = exp(att)/sum(exp(att)) exactly.  This
// removes the online-rescale recurrence -> flat FMA accumulation, 2x edge
// unroll for ILP.  Per edge: 2 coalesced float4 gathers, 3-shfl dot reduce,
// 1 exp, 9 FMA.
// ---------------------------------------------------------------------------
__global__ void fused_kernel(const float* __restrict__ x,
                             const float* __restrict__ rn,
                             const float* __restrict__ beta,
                             const int* __restrict__ row_ptr,
                             const int* __restrict__ col,
                             float* __restrict__ out, int N) {
    int wid  = blockIdx.x * (blockDim.x >> 6) + (threadIdx.x >> 6);
    int lane = threadIdx.x & 63;
    int g    = lane >> 3;               // group id (row slot)
    int sub  = lane & 7;                // lane within group
    int r    = wid * 8 + g;
    bool rv  = (r < N);

    int start = 0, deg = 0;
    if (rv) {
        start = row_ptr[r];
        deg   = row_ptr[r + 1] - start;
    }

    const char* xB   = (const char*)x;
    uint        subo = (uint)sub << 4;  // this lane's float4 byte offset

    // col/rn chunk: lanes hold edges start+k..start+k+7 of their group's row
    int   cols8 = 0;
    float rns8  = 0.f;
    if (sub < deg) {
        cols8 = col[start + sub];
        rns8  = rn[cols8];
    }

    // x_r, normalized and beta-scaled: att = (beta*rn_r*x_r) . x_c * rn_c
    float4 xa = make_float4(0.f, 0.f, 0.f, 0.f);
    float4 xb = make_float4(0.f, 0.f, 0.f, 0.f);
    if (rv) {
        uint roff = ((uint)r << 8) + subo;
        xa = *reinterpret_cast<const float4*>(xB + roff);
        xb = *reinterpret_cast<const float4*>(xB + roff + 128);
        float brn = beta[0] * rn[r];
        xa.x *= brn; xa.y *= brn; xa.z *= brn; xa.w *= brn;
        xb.x *= brn; xb.y *= brn; xb.z *= brn; xb.w *= brn;
    }

    float  s = 0.f;
    float4 aa = make_float4(0.f, 0.f, 0.f, 0.f);
    float4 ab = make_float4(0.f, 0.f, 0.f, 0.f);

    for (int k = 0; k < deg; k += 2) {
        int kk = k & 7;
        // chunk reload once per 8 edges (k even -> pairs never straddle)
        if (k && kk == 0) {
            if (k + sub < deg) {
                cols8 = col[start + k + sub];
                rns8  = rn[cols8];
            }
        }
        int   c0  = __shfl(cols8, kk, 8);
        float rn0 = __shfl(rns8,  kk, 8);
        int   c1  = __shfl(cols8, kk + 1, 8);
        float rn1 = __shfl(rns8,  kk + 1, 8);
        bool  v1  = (k + 1) < deg;

        uint o0 = ((uint)c0 << 8) + subo;
        float4 va0 = *reinterpret_cast<const float4*>(xB + o0);
        float4 vb0 = *reinterpret_cast<const float4*>(xB + o0 + 128);
        float4 va1 = make_float4(0.f, 0.f, 0.f, 0.f);
        float4 vb1 = make_float4(0.f, 0.f, 0.f, 0.f);
        if (v1) {
            uint o1 = ((uint)c1 << 8) + subo;
            va1 = *reinterpret_cast<const float4*>(xB + o1);
            vb1 = *reinterpret_cast<const float4*>(xB + o1 + 128);
        }

        // two independent dot chains, interleaved shfl reduces
        float d0 = xa.x*va0.x + xa.y*va0.y + xa.z*va0.z + xa.w*va0.w
                 + xb.x*vb0.x + xb.y*vb0.y + xb.z*vb0.z + xb.w*vb0.w;
        float d1 = xa.x*va1.x + xa.y*va1.y + xa.z*va1.z + xa.w*va1.w
                 + xb.x*vb1.x + xb.y*vb1.y + xb.z*vb1.z + xb.w*vb1.w;
        d0 += __shfl_xor(d0, 1);  d1 += __shfl_xor(d1, 1);
        d0 += __shfl_xor(d0, 2);  d1 += __shfl_xor(d1, 2);
        d0 += __shfl_xor(d0, 4);  d1 += __shfl_xor(d1, 4);

        float e0 = __expf(d0 * rn0);            // bounded by e^|beta|
        float e1 = v1 ? __expf(d1 * rn1) : 0.f;
        s += e0 + e1;

        aa.x += e0 * va0.x + e1 * va1.x;  aa.y += e0 * va0.y + e1 * va1.y;
        aa.z += e0 * va0.z + e1 * va1.z;  aa.w += e0 * va0.w + e1 * va1.w;
        ab.x += e0 * vb0.x + e1 * vb1.x;  ab.y += e0 * vb0.y + e1 * vb1.y;
        ab.z += e0 * vb0.z + e1 * vb1.z;  ab.w += e0 * vb0.w + e1 * vb1.w;
    }

    // deg==0 rows: s=0, acc=0 -> out=0 (matches reference empty-row guard)
    float inv = 1.0f / fmaxf(s, 1e-16f);
    if (rv) {
        uint roff = ((uint)r << 8) + subo;
        *reinterpret_cast<float4*>((char*)out + roff) =
            make_float4(aa.x * inv, aa.y * inv, aa.z * inv, aa.w * inv);
        *reinterpret_cast<float4*>((char*)out + roff + 128) =
            make_float4(ab.x * inv, ab.y * inv, ab.z * inv, ab.w * inv);
    }
}

// ---------------------------------------------------------------------------
extern "C" void kernel_launch(void* const* d_in, const int* in_sizes, int n_in,
                              void* d_out, int out_size, void* d_ws, size_t ws_size,
                              hipStream_t stream) {
    const float* x    = (const float*)d_in[0];
    const float* beta = (const float*)d_in[1];
    const int*   row  = (const int*)d_in[2];
    const int*   col  = (const int*)d_in[3];
    float*       out  = (float*)d_out;

    const int N = in_sizes[0] / FEAT;   // 50000
    const int E = in_sizes[2];          // 800000

    // Workspace layout: rn[N] | row_ptr[N+1]
    float* rn      = (float*)d_ws;
    int*   row_ptr = (int*)(rn + ((N + 63) & ~63));

    {   // merged prep: norms (32 rows/block) + rowptr build (256 edges/block)
        int normBlocks = (N + 31) / 32;
        int edgeBlocks = (E + 255) / 256;
        prep_kernel<<<normBlocks + edgeBlocks, 256, 0, stream>>>(
            x, rn, row, row_ptr, N, E, normBlocks);
    }
    {   // fused: 8 rows per wave, 4 waves per block -> 32 rows per block
        int waves = (N + 7) / 8;
        int grid  = (waves + 3) / 4;
        fused_kernel<<<grid, 256, 0, stream>>>(x, rn, beta, row_ptr, col, out, N);
    }
}

// Round 7
// 40.034 us; speedup vs baseline: 5.1081x; 1.0419x over previous
//
#include <hip/hip_runtime.h>
#include <hip/hip_bf16.h>

#define FEAT 64

// ---------------------------------------------------------------------------
// Kernel 1 (merged prep): blocks [0, normBlocks) compute inverse L2 norms
// (8-lane group per row, 8 rows per wave, 32 rows per block); remaining
// blocks build row_ptr[N+1] from the SORTED row_index.
// ---------------------------------------------------------------------------
__global__ void prep_kernel(const float* __restrict__ x,
                            float* __restrict__ rn,
                            const int* __restrict__ row,
                            int* __restrict__ row_ptr,
                            int N, int E, int normBlocks) {
    if ((int)blockIdx.x < normBlocks) {
        int wid  = blockIdx.x * (blockDim.x >> 6) + (threadIdx.x >> 6);
        int lane = threadIdx.x & 63;
        int g    = lane >> 3;
        int sub  = lane & 7;
        int r    = wid * 8 + g;
        if (r >= N) return;
        const char* xB = (const char*)x;
        uint roff = ((uint)r << 8) + ((uint)sub << 4);
        float4 xa = *reinterpret_cast<const float4*>(xB + roff);
        float4 xb = *reinterpret_cast<const float4*>(xB + roff + 128);
        float q = xa.x*xa.x + xa.y*xa.y + xa.z*xa.z + xa.w*xa.w
                + xb.x*xb.x + xb.y*xb.y + xb.z*xb.z + xb.w*xb.w;
        q += __shfl_xor(q, 1);
        q += __shfl_xor(q, 2);
        q += __shfl_xor(q, 4);
        if (sub == 0) rn[r] = rsqrtf(q + 1e-8f);
    } else {
        int e = (blockIdx.x - normBlocks) * blockDim.x + threadIdx.x;
        if (e >= E) return;
        int curr = row[e];
        if (e == 0) {
            for (int r = 0; r <= curr; ++r) row_ptr[r] = 0;
        } else {
            int prev = row[e - 1];
            for (int r = prev + 1; r <= curr; ++r) row_ptr[r] = e;
        }
        if (e == E - 1) {
            for (int r = curr + 1; r <= N; ++r) row_ptr[r] = E;
        }
    }
}

// ---------------------------------------------------------------------------
// Kernel 2: FUSED attention + shift-free softmax + aggregation.
// TWO 8-lane groups per row (16 lanes/row, 4 rows/wave).  Shift-free softmax
// (att = beta*cos_sim bounded by |beta|; exp cannot overflow) makes the
// partial (s, acc) sums plainly additive, so the two groups process
// interleaved edge pairs independently and merge with 9 shfl_xor(8) adds.
// col/rn chunks are double-buffered (A/B) so the col->shfl->gather chain is
// off the critical path.  Per group-iteration: 2 edges, 4 coalesced float4
// gathers, 2x 3-shfl dot reduce, 2 exp, ~18 FMA.
// ---------------------------------------------------------------------------
__global__ void fused_kernel(const float* __restrict__ x,
                             const float* __restrict__ rn,
                             const float* __restrict__ beta,
                             const int* __restrict__ row_ptr,
                             const int* __restrict__ col,
                             float* __restrict__ out, int N) {
    int wid  = blockIdx.x * (blockDim.x >> 6) + (threadIdx.x >> 6);
    int lane = threadIdx.x & 63;
    int slot = lane >> 4;               // row slot within wave (0..3)
    int h    = (lane >> 3) & 1;         // half-group id within row
    int sub  = lane & 7;                // lane within group
    int r    = wid * 4 + slot;
    bool rv  = (r < N);

    int start = 0, deg = 0;
    if (rv) {
        start = row_ptr[r];
        deg   = row_ptr[r + 1] - start;
    }

    const char* xB   = (const char*)x;
    uint        subo = (uint)sub << 4;  // this lane's float4 byte offset

    // col/rn chunks, double-buffered: A = current 8 edges, B = next 8
    int   colsA = 0, colsB = 0;
    float rnsA  = 0.f, rnsB = 0.f;
    if (sub < deg)     { colsA = col[start + sub];     rnsA = rn[colsA]; }
    if (8 + sub < deg) { colsB = col[start + 8 + sub]; rnsB = rn[colsB]; }

    // x_r, normalized and beta-scaled: att = (beta*rn_r*x_r) . x_c * rn_c
    float4 xa = make_float4(0.f, 0.f, 0.f, 0.f);
    float4 xb = make_float4(0.f, 0.f, 0.f, 0.f);
    if (rv) {
        uint roff = ((uint)r << 8) + subo;
        xa = *reinterpret_cast<const float4*>(xB + roff);
        xb = *reinterpret_cast<const float4*>(xB + roff + 128);
        float brn = beta[0] * rn[r];
        xa.x *= brn; xa.y *= brn; xa.z *= brn; xa.w *= brn;
        xb.x *= brn; xb.y *= brn; xb.z *= brn; xb.w *= brn;
    }

    float  s = 0.f;
    float4 aa = make_float4(0.f, 0.f, 0.f, 0.f);
    float4 ab = make_float4(0.f, 0.f, 0.f, 0.f);

    // Group h handles edges {base+2h, base+2h+1}; base advances by 4.
    for (int base = 0; base < deg; base += 4) {
        if (base && (base & 7) == 0) {      // chunk rotate + prefetch next
            colsA = colsB;  rnsA = rnsB;
            if (base + 8 + sub < deg) {
                colsB = col[start + base + 8 + sub];
                rnsB  = rn[colsB];
            }
        }
        int  k0 = base + 2 * h;
        int  kk = (base & 7) + 2 * h;       // position inside chunk A
        bool v0 = k0 < deg;
        bool v1 = k0 + 1 < deg;

        int   c0  = __shfl(colsA, kk, 8);
        float rn0 = __shfl(rnsA,  kk, 8);
        int   c1  = __shfl(colsA, kk + 1, 8);
        float rn1 = __shfl(rnsA,  kk + 1, 8);

        float4 va0 = make_float4(0.f, 0.f, 0.f, 0.f);
        float4 vb0 = make_float4(0.f, 0.f, 0.f, 0.f);
        float4 va1 = make_float4(0.f, 0.f, 0.f, 0.f);
        float4 vb1 = make_float4(0.f, 0.f, 0.f, 0.f);
        if (v0) {
            uint o0 = ((uint)c0 << 8) + subo;
            va0 = *reinterpret_cast<const float4*>(xB + o0);
            vb0 = *reinterpret_cast<const float4*>(xB + o0 + 128);
        }
        if (v1) {
            uint o1 = ((uint)c1 << 8) + subo;
            va1 = *reinterpret_cast<const float4*>(xB + o1);
            vb1 = *reinterpret_cast<const float4*>(xB + o1 + 128);
        }

        // two independent dot chains, interleaved shfl reduces
        float d0 = xa.x*va0.x + xa.y*va0.y + xa.z*va0.z + xa.w*va0.w
                 + xb.x*vb0.x + xb.y*vb0.y + xb.z*vb0.z + xb.w*vb0.w;
        float d1 = xa.x*va1.x + xa.y*va1.y + xa.z*va1.z + xa.w*va1.w
                 + xb.x*vb1.x + xb.y*vb1.y + xb.z*vb1.z + xb.w*vb1.w;
        d0 += __shfl_xor(d0, 1);  d1 += __shfl_xor(d1, 1);
        d0 += __shfl_xor(d0, 2);  d1 += __shfl_xor(d1, 2);
        d0 += __shfl_xor(d0, 4);  d1 += __shfl_xor(d1, 4);

        float e0 = v0 ? __expf(d0 * rn0) : 0.f;   // bounded by e^|beta|
        float e1 = v1 ? __expf(d1 * rn1) : 0.f;
        s += e0 + e1;

        aa.x += e0 * va0.x + e1 * va1.x;  aa.y += e0 * va0.y + e1 * va1.y;
        aa.z += e0 * va0.z + e1 * va1.z;  aa.w += e0 * va0.w + e1 * va1.w;
        ab.x += e0 * vb0.x + e1 * vb1.x;  ab.y += e0 * vb0.y + e1 * vb1.y;
        ab.z += e0 * vb0.z + e1 * vb1.z;  ab.w += e0 * vb0.w + e1 * vb1.w;
    }

    // merge the two half-groups of each row (plain adds: shift-free softmax)
    s    += __shfl_xor(s, 8);
    aa.x += __shfl_xor(aa.x, 8);  aa.y += __shfl_xor(aa.y, 8);
    aa.z += __shfl_xor(aa.z, 8);  aa.w += __shfl_xor(aa.w, 8);
    ab.x += __shfl_xor(ab.x, 8);  ab.y += __shfl_xor(ab.y, 8);
    ab.z += __shfl_xor(ab.z, 8);  ab.w += __shfl_xor(ab.w, 8);

    // deg==0 rows: s=0, acc=0 -> out=0 (matches reference empty-row guard)
    float inv = 1.0f / fmaxf(s, 1e-16f);
    if (rv) {
        // 16 lanes per row store 64 floats: h selects which half this lane owns
        float4 o = h ? ab : aa;
        uint roff = ((uint)r << 8) + subo + ((uint)h << 7);
        *reinterpret_cast<float4*>((char*)out + roff) =
            make_float4(o.x * inv, o.y * inv, o.z * inv, o.w * inv);
    }
}

// ---------------------------------------------------------------------------
extern "C" void kernel_launch(void* const* d_in, const int* in_sizes, int n_in,
                              void* d_out, int out_size, void* d_ws, size_t ws_size,
                              hipStream_t stream) {
    const float* x    = (const float*)d_in[0];
    const float* beta = (const float*)d_in[1];
    const int*   row  = (const int*)d_in[2];
    const int*   col  = (const int*)d_in[3];
    float*       out  = (float*)d_out;

    const int N = in_sizes[0] / FEAT;   // 50000
    const int E = in_sizes[2];          // 800000

    // Workspace layout: rn[N] | row_ptr[N+1]
    float* rn      = (float*)d_ws;
    int*   row_ptr = (int*)(rn + ((N + 63) & ~63));

    {   // merged prep: norms (32 rows/block) + rowptr build (256 edges/block)
        int normBlocks = (N + 31) / 32;
        int edgeBlocks = (E + 255) / 256;
        prep_kernel<<<normBlocks + edgeBlocks, 256, 0, stream>>>(
            x, rn, row, row_ptr, N, E, normBlocks);
    }
    {   // fused: 4 rows per wave (2 groups/row), 4 waves/block -> 16 rows/block
        int waves = (N + 3) / 4;
        int grid  = (waves + 3) / 4;
        fused_kernel<<<grid, 256, 0, stream>>>(x, rn, beta, row_ptr, col, out, N);
    }
}

// Round 8
// 38.293 us; speedup vs baseline: 5.3404x; 1.0455x over previous
//
#include <hip/hip_runtime.h>
#include <hip/hip_bf16.h>

#define FEAT 64

// RNE pack of two fp32 into one u32 of 2 bf16 (lo, hi)
__device__ inline uint packbf2(float lo, float hi) {
    uint ul = __float_as_uint(lo), uh = __float_as_uint(hi);
    ul += 0x7FFFu + ((ul >> 16) & 1u);
    uh += 0x7FFFu + ((uh >> 16) & 1u);
    return (ul >> 16) | (uh & 0xFFFF0000u);
}

// unpack uint4 (8 bf16) -> two float4
__device__ inline void unpack8(uint4 q, float4& va, float4& vb) {
    va.x = __uint_as_float(q.x << 16);
    va.y = __uint_as_float(q.x & 0xFFFF0000u);
    va.z = __uint_as_float(q.y << 16);
    va.w = __uint_as_float(q.y & 0xFFFF0000u);
    vb.x = __uint_as_float(q.z << 16);
    vb.y = __uint_as_float(q.z & 0xFFFF0000u);
    vb.z = __uint_as_float(q.w << 16);
    vb.w = __uint_as_float(q.w & 0xFFFF0000u);
}

// ---------------------------------------------------------------------------
// Kernel 1 (merged prep): blocks [0, normBlocks): inverse L2 norms + bf16
// mirror of x (feature-permuted so lane sub holds features [4s,4s+4) and
// [32+4s,32+4s+4) in one uint4).  Remaining blocks: row_ptr[N+1] build from
// the SORTED row_index.
// ---------------------------------------------------------------------------
__global__ void prep_kernel(const float* __restrict__ x,
                            float* __restrict__ rn,
                            uint4* __restrict__ xh,      // may be null
                            const int* __restrict__ row,
                            int* __restrict__ row_ptr,
                            int N, int E, int normBlocks) {
    if ((int)blockIdx.x < normBlocks) {
        int wid  = blockIdx.x * (blockDim.x >> 6) + (threadIdx.x >> 6);
        int lane = threadIdx.x & 63;
        int g    = lane >> 3;
        int sub  = lane & 7;
        int r    = wid * 8 + g;
        if (r >= N) return;
        const char* xB = (const char*)x;
        uint roff = ((uint)r << 8) + ((uint)sub << 4);
        float4 xa = *reinterpret_cast<const float4*>(xB + roff);
        float4 xb = *reinterpret_cast<const float4*>(xB + roff + 128);
        float q = xa.x*xa.x + xa.y*xa.y + xa.z*xa.z + xa.w*xa.w
                + xb.x*xb.x + xb.y*xb.y + xb.z*xb.z + xb.w*xb.w;
        q += __shfl_xor(q, 1);
        q += __shfl_xor(q, 2);
        q += __shfl_xor(q, 4);
        if (sub == 0) rn[r] = rsqrtf(q + 1e-8f);
        if (xh) {
            uint4 p;
            p.x = packbf2(xa.x, xa.y);
            p.y = packbf2(xa.z, xa.w);
            p.z = packbf2(xb.x, xb.y);
            p.w = packbf2(xb.z, xb.w);
            xh[r * 8 + sub] = p;
        }
    } else {
        int e = (blockIdx.x - normBlocks) * blockDim.x + threadIdx.x;
        if (e >= E) return;
        int curr = row[e];
        if (e == 0) {
            for (int r = 0; r <= curr; ++r) row_ptr[r] = 0;
        } else {
            int prev = row[e - 1];
            for (int r = prev + 1; r <= curr; ++r) row_ptr[r] = e;
        }
        if (e == E - 1) {
            for (int r = curr + 1; r <= N; ++r) row_ptr[r] = E;
        }
    }
}

// ---------------------------------------------------------------------------
// Kernel 2: FUSED attention + shift-free softmax + aggregation, bf16 gathers.
// One 8-lane group per row, 8 rows per wave.  Per edge: ONE dwordx4 gather
// (128B bf16 row), unpack, 8-FMA dot, 3-shfl reduce, exp, 8-FMA accumulate.
// 4-edge software pipeline: loads for edges k+4..k+7 are issued before
// processing k..k+3 (col/rn chunks double-buffered 8 ahead), keeping >=4
// independent gathers in flight per wave.
// ---------------------------------------------------------------------------
__global__ void fused_bf16_kernel(const float* __restrict__ x,
                                  const uint4* __restrict__ xh,
                                  const float* __restrict__ rn,
                                  const float* __restrict__ beta,
                                  const int* __restrict__ row_ptr,
                                  const int* __restrict__ col,
                                  float* __restrict__ out, int N) {
    int wid  = blockIdx.x * (blockDim.x >> 6) + (threadIdx.x >> 6);
    int lane = threadIdx.x & 63;
    int g    = lane >> 3;               // group = row slot (0..7)
    int sub  = lane & 7;
    int r    = wid * 8 + g;
    bool rv  = (r < N);

    int start = 0, deg = 0;
    if (rv) {
        start = row_ptr[r];
        deg   = row_ptr[r + 1] - start;
    }

    // col/rn chunks: A = edges [a, a+8), B = [a+8, a+16)
    int   colsA = 0, colsB = 0;
    float rnsA  = 0.f, rnsB = 0.f;
    if (sub < deg)     { colsA = col[start + sub];     rnsA = rn[colsA]; }
    if (8 + sub < deg) { colsB = col[start + 8 + sub]; rnsB = rn[colsB]; }

    // x_r fp32, scaled by beta*rn_r:  att = (beta*rn_r*x_r) . x_c * rn_c
    float4 xa = make_float4(0.f, 0.f, 0.f, 0.f);
    float4 xb = make_float4(0.f, 0.f, 0.f, 0.f);
    if (rv) {
        const char* xB = (const char*)x;
        uint roff = ((uint)r << 8) + ((uint)sub << 4);
        xa = *reinterpret_cast<const float4*>(xB + roff);
        xb = *reinterpret_cast<const float4*>(xB + roff + 128);
        float brn = beta[0] * rn[r];
        xa.x *= brn; xa.y *= brn; xa.z *= brn; xa.w *= brn;
        xb.x *= brn; xb.y *= brn; xb.z *= brn; xb.w *= brn;
    }

    float  s = 0.f;
    float4 aa = make_float4(0.f, 0.f, 0.f, 0.f);
    float4 ab = make_float4(0.f, 0.f, 0.f, 0.f);

    uint4 z4 = make_uint4(0u, 0u, 0u, 0u);
    uint4 q0 = z4, q1 = z4, q2 = z4, q3 = z4;
    float rn0 = 0.f, rn1 = 0.f, rn2 = 0.f, rn3 = 0.f;

    // prologue: fetch edges 0..3 (chunk A, kk 0..3)
    {
        int   c0 = __shfl(colsA, 0, 8), c1 = __shfl(colsA, 1, 8);
        int   c2 = __shfl(colsA, 2, 8), c3 = __shfl(colsA, 3, 8);
        rn0 = __shfl(rnsA, 0, 8);  rn1 = __shfl(rnsA, 1, 8);
        rn2 = __shfl(rnsA, 2, 8);  rn3 = __shfl(rnsA, 3, 8);
        if (0 < deg) q0 = xh[c0 * 8 + sub];
        if (1 < deg) q1 = xh[c1 * 8 + sub];
        if (2 < deg) q2 = xh[c2 * 8 + sub];
        if (3 < deg) q3 = xh[c3 * 8 + sub];
    }

    for (int base = 0; base < deg; base += 4) {
        // rotate chunks at 8-boundaries; refill B two iterations ahead
        if (base && (base & 7) == 0) {
            colsA = colsB;  rnsA = rnsB;
            colsB = 0;      rnsB = 0.f;
            if (base + 8 + sub < deg) {
                colsB = col[start + base + 8 + sub];
                rnsB  = rn[colsB];
            }
        }
        // issue loads for next quad (edges base+4..base+7)
        int  nb  = base + 4;
        int  nkk = nb & 7;                       // 4 -> in A, 0 -> in B
        int   cS = (nkk == 4) ? colsA : colsB;
        float rS = (nkk == 4) ? rnsA  : rnsB;
        int   nc0 = __shfl(cS, nkk + 0, 8), nc1 = __shfl(cS, nkk + 1, 8);
        int   nc2 = __shfl(cS, nkk + 2, 8), nc3 = __shfl(cS, nkk + 3, 8);
        float nr0 = __shfl(rS, nkk + 0, 8), nr1 = __shfl(rS, nkk + 1, 8);
        float nr2 = __shfl(rS, nkk + 2, 8), nr3 = __shfl(rS, nkk + 3, 8);
        uint4 nq0 = z4, nq1 = z4, nq2 = z4, nq3 = z4;
        if (nb + 0 < deg) nq0 = xh[nc0 * 8 + sub];
        if (nb + 1 < deg) nq1 = xh[nc1 * 8 + sub];
        if (nb + 2 < deg) nq2 = xh[nc2 * 8 + sub];
        if (nb + 3 < deg) nq3 = xh[nc3 * 8 + sub];

        // process current quad
        float4 va0, vb0, va1, vb1, va2, vb2, va3, vb3;
        unpack8(q0, va0, vb0);  unpack8(q1, va1, vb1);
        unpack8(q2, va2, vb2);  unpack8(q3, va3, vb3);

        float d0 = xa.x*va0.x + xa.y*va0.y + xa.z*va0.z + xa.w*va0.w
                 + xb.x*vb0.x + xb.y*vb0.y + xb.z*vb0.z + xb.w*vb0.w;
        float d1 = xa.x*va1.x + xa.y*va1.y + xa.z*va1.z + xa.w*va1.w
                 + xb.x*vb1.x + xb.y*vb1.y + xb.z*vb1.z + xb.w*vb1.w;
        float d2 = xa.x*va2.x + xa.y*va2.y + xa.z*va2.z + xa.w*va2.w
                 + xb.x*vb2.x + xb.y*vb2.y + xb.z*vb2.z + xb.w*vb2.w;
        float d3 = xa.x*va3.x + xa.y*va3.y + xa.z*va3.z + xa.w*va3.w
                 + xb.x*vb3.x + xb.y*vb3.y + xb.z*vb3.z + xb.w*vb3.w;
        d0 += __shfl_xor(d0, 1);  d1 += __shfl_xor(d1, 1);
        d2 += __shfl_xor(d2, 1);  d3 += __shfl_xor(d3, 1);
        d0 += __shfl_xor(d0, 2);  d1 += __shfl_xor(d1, 2);
        d2 += __shfl_xor(d2, 2);  d3 += __shfl_xor(d3, 2);
        d0 += __shfl_xor(d0, 4);  d1 += __shfl_xor(d1, 4);
        d2 += __shfl_xor(d2, 4);  d3 += __shfl_xor(d3, 4);

        float e0 = (base + 0 < deg) ? __expf(d0 * rn0) : 0.f;
        float e1 = (base + 1 < deg) ? __expf(d1 * rn1) : 0.f;
        float e2 = (base + 2 < deg) ? __expf(d2 * rn2) : 0.f;
        float e3 = (base + 3 < deg) ? __expf(d3 * rn3) : 0.f;
        s += (e0 + e1) + (e2 + e3);

        aa.x += e0*va0.x + e1*va1.x + e2*va2.x + e3*va3.x;
        aa.y += e0*va0.y + e1*va1.y + e2*va2.y + e3*va3.y;
        aa.z += e0*va0.z + e1*va1.z + e2*va2.z + e3*va3.z;
        aa.w += e0*va0.w + e1*va1.w + e2*va2.w + e3*va3.w;
        ab.x += e0*vb0.x + e1*vb1.x + e2*vb2.x + e3*vb3.x;
        ab.y += e0*vb0.y + e1*vb1.y + e2*vb2.y + e3*vb3.y;
        ab.z += e0*vb0.z + e1*vb1.z + e2*vb2.z + e3*vb3.z;
        ab.w += e0*vb0.w + e1*vb1.w + e2*vb2.w + e3*vb3.w;

        q0 = nq0; q1 = nq1; q2 = nq2; q3 = nq3;
        rn0 = nr0; rn1 = nr1; rn2 = nr2; rn3 = nr3;
    }

    float inv = 1.0f / fmaxf(s, 1e-16f);      // deg==0 -> out = 0
    if (rv) {
        uint roff = ((uint)r << 8) + ((uint)sub << 4);
        *reinterpret_cast<float4*>((char*)out + roff) =
            make_float4(aa.x * inv, aa.y * inv, aa.z * inv, aa.w * inv);
        *reinterpret_cast<float4*>((char*)out + roff + 128) =
            make_float4(ab.x * inv, ab.y * inv, ab.z * inv, ab.w * inv);
    }
}

// ---------------------------------------------------------------------------
// Fallback (fp32 gathers) if workspace can't hold the bf16 mirror:
// round-7 kernel, 2 groups/row.
// ---------------------------------------------------------------------------
__global__ void fused_kernel(const float* __restrict__ x,
                             const float* __restrict__ rn,
                             const float* __restrict__ beta,
                             const int* __restrict__ row_ptr,
                             const int* __restrict__ col,
                             float* __restrict__ out, int N) {
    int wid  = blockIdx.x * (blockDim.x >> 6) + (threadIdx.x >> 6);
    int lane = threadIdx.x & 63;
    int slot = lane >> 4;
    int h    = (lane >> 3) & 1;
    int sub  = lane & 7;
    int r    = wid * 4 + slot;
    bool rv  = (r < N);

    int start = 0, deg = 0;
    if (rv) {
        start = row_ptr[r];
        deg   = row_ptr[r + 1] - start;
    }

    const char* xB   = (const char*)x;
    uint        subo = (uint)sub << 4;

    int   colsA = 0, colsB = 0;
    float rnsA  = 0.f, rnsB = 0.f;
    if (sub < deg)     { colsA = col[start + sub];     rnsA = rn[colsA]; }
    if (8 + sub < deg) { colsB = col[start + 8 + sub]; rnsB = rn[colsB]; }

    float4 xa = make_float4(0.f, 0.f, 0.f, 0.f);
    float4 xb = make_float4(0.f, 0.f, 0.f, 0.f);
    if (rv) {
        uint roff = ((uint)r << 8) + subo;
        xa = *reinterpret_cast<const float4*>(xB + roff);
        xb = *reinterpret_cast<const float4*>(xB + roff + 128);
        float brn = beta[0] * rn[r];
        xa.x *= brn; xa.y *= brn; xa.z *= brn; xa.w *= brn;
        xb.x *= brn; xb.y *= brn; xb.z *= brn; xb.w *= brn;
    }

    float  s = 0.f;
    float4 aa = make_float4(0.f, 0.f, 0.f, 0.f);
    float4 ab = make_float4(0.f, 0.f, 0.f, 0.f);

    for (int base = 0; base < deg; base += 4) {
        if (base && (base & 7) == 0) {
            colsA = colsB;  rnsA = rnsB;
            if (base + 8 + sub < deg) {
                colsB = col[start + base + 8 + sub];
                rnsB  = rn[colsB];
            }
        }
        int  k0 = base + 2 * h;
        int  kk = (base & 7) + 2 * h;
        bool v0 = k0 < deg;
        bool v1 = k0 + 1 < deg;

        int   c0  = __shfl(colsA, kk, 8);
        float rw0 = __shfl(rnsA,  kk, 8);
        int   c1  = __shfl(colsA, kk + 1, 8);
        float rw1 = __shfl(rnsA,  kk + 1, 8);

        float4 va0 = make_float4(0.f, 0.f, 0.f, 0.f);
        float4 vb0 = make_float4(0.f, 0.f, 0.f, 0.f);
        float4 va1 = make_float4(0.f, 0.f, 0.f, 0.f);
        float4 vb1 = make_float4(0.f, 0.f, 0.f, 0.f);
        if (v0) {
            uint o0 = ((uint)c0 << 8) + subo;
            va0 = *reinterpret_cast<const float4*>(xB + o0);
            vb0 = *reinterpret_cast<const float4*>(xB + o0 + 128);
        }
        if (v1) {
            uint o1 = ((uint)c1 << 8) + subo;
            va1 = *reinterpret_cast<const float4*>(xB + o1);
            vb1 = *reinterpret_cast<const float4*>(xB + o1 + 128);
        }

        float d0 = xa.x*va0.x + xa.y*va0.y + xa.z*va0.z + xa.w*va0.w
                 + xb.x*vb0.x + xb.y*vb0.y + xb.z*vb0.z + xb.w*vb0.w;
        float d1 = xa.x*va1.x + xa.y*va1.y + xa.z*va1.z + xa.w*va1.w
                 + xb.x*vb1.x + xb.y*vb1.y + xb.z*vb1.z + xb.w*vb1.w;
        d0 += __shfl_xor(d0, 1);  d1 += __shfl_xor(d1, 1);
        d0 += __shfl_xor(d0, 2);  d1 += __shfl_xor(d1, 2);
        d0 += __shfl_xor(d0, 4);  d1 += __shfl_xor(d1, 4);

        float e0 = v0 ? __expf(d0 * rw0) : 0.f;
        float e1 = v1 ? __expf(d1 * rw1) : 0.f;
        s += e0 + e1;

        aa.x += e0 * va0.x + e1 * va1.x;  aa.y += e0 * va0.y + e1 * va1.y;
        aa.z += e0 * va0.z + e1 * va1.z;  aa.w += e0 * va0.w + e1 * va1.w;
        ab.x += e0 * vb0.x + e1 * vb1.x;  ab.y += e0 * vb0.y + e1 * vb1.y;
        ab.z += e0 * vb0.z + e1 * vb1.z;  ab.w += e0 * vb0.w + e1 * vb1.w;
    }

    s    += __shfl_xor(s, 8);
    aa.x += __shfl_xor(aa.x, 8);  aa.y += __shfl_xor(aa.y, 8);
    aa.z += __shfl_xor(aa.z, 8);  aa.w += __shfl_xor(aa.w, 8);
    ab.x += __shfl_xor(ab.x, 8);  ab.y += __shfl_xor(ab.y, 8);
    ab.z += __shfl_xor(ab.z, 8);  ab.w += __shfl_xor(ab.w, 8);

    float inv = 1.0f / fmaxf(s, 1e-16f);
    if (rv) {
        float4 o = h ? ab : aa;
        uint roff = ((uint)r << 8) + subo + ((uint)h << 7);
        *reinterpret_cast<float4*>((char*)out + roff) =
            make_float4(o.x * inv, o.y * inv, o.z * inv, o.w * inv);
    }
}

// ---------------------------------------------------------------------------
extern "C" void kernel_launch(void* const* d_in, const int* in_sizes, int n_in,
                              void* d_out, int out_size, void* d_ws, size_t ws_size,
                              hipStream_t stream) {
    const float* x    = (const float*)d_in[0];
    const float* beta = (const float*)d_in[1];
    const int*   row  = (const int*)d_in[2];
    const int*   col  = (const int*)d_in[3];
    float*       out  = (float*)d_out;

    const int N = in_sizes[0] / FEAT;   // 50000
    const int E = in_sizes[2];          // 800000

    // Workspace layout: rn[N] | row_ptr[N+1] | xh[N*64 bf16]  (512B-aligned)
    char*  ws      = (char*)d_ws;
    size_t off_rp  = ((size_t)(N + 64) * 4 + 511) & ~(size_t)511;
    size_t off_xh  = off_rp + (((size_t)(N + 1) * 4 + 511) & ~(size_t)511);
    size_t need    = off_xh + (size_t)N * 128;

    float* rn      = (float*)ws;
    int*   row_ptr = (int*)(ws + off_rp);
    uint4* xh      = (ws_size >= need) ? (uint4*)(ws + off_xh) : nullptr;

    {   // merged prep: norms (+ bf16 mirror) + rowptr build
        int normBlocks = (N + 31) / 32;
        int edgeBlocks = (E + 255) / 256;
        prep_kernel<<<normBlocks + edgeBlocks, 256, 0, stream>>>(
            x, rn, xh, row, row_ptr, N, E, normBlocks);
    }
    if (xh) {   // bf16-gather fused: 8 rows/wave, 4 waves/block
        int waves = (N + 7) / 8;
        int grid  = (waves + 3) / 4;
        fused_bf16_kernel<<<grid, 256, 0, stream>>>(
            x, xh, rn, beta, row_ptr, col, out, N);
    } else {    // fp32 fallback: 4 rows/wave (2 groups/row)
        int waves = (N + 3) / 4;
        int grid  = (waves + 3) / 4;
        fused_kernel<<<grid, 256, 0, stream>>>(
            x, rn, beta, row_ptr, col, out, N);
    }
}